// Round 20
// baseline (116.223 us; speedup 1.0000x reference)
//
#include <hip/hip_runtime.h>
#include <hip/hip_bf16.h>
#include <math.h>

typedef __attribute__((ext_vector_type(8))) __bf16 bf16x8;
typedef __attribute__((ext_vector_type(4))) float f32x4;

#define NTOK 8192
#define DIN 1024
#define DOUT 1024
#define KAUG 4096
#define SEH 32

#define BK 64
#define NKT (KAUG / BK)  // 64 K-tiles, no split-K

static __device__ __forceinline__ unsigned short f2bf(float f) {
  union { float f; unsigned u; } v; v.f = f;
  unsigned r = (v.u + 0x7FFFu + ((v.u >> 16) & 1u)) >> 16;
  return (unsigned short)r;
}

// Merged prep:
//  A-part (8192 blocks): 4 elems/thread, 16B read / 32B write per lane.
//  W-part (4096 blocks): row-major Waug pack.
//  SE-part (512 blocks): w1/w2 packed as bf16 HI + LO planes (w = hi + lo).
__global__ __launch_bounds__(256) void prep(const float* __restrict__ x,
                                            const float* __restrict__ bw,
                                            const float* __restrict__ sw,
                                            const float* __restrict__ w1,
                                            const float* __restrict__ w2,
                                            ushort* __restrict__ Aaug,
                                            ushort* __restrict__ Waug,
                                            ushort* __restrict__ w1b,
                                            ushort* __restrict__ w1lo,
                                            ushort* __restrict__ w2b,
                                            ushort* __restrict__ w2lo) {
  const int b = blockIdx.x;
  if (b < 8192) {
    const int id4 = b * 256 + threadIdx.x;  // over NTOK*DIN/4
    const float4 xv = ((const float4*)x)[id4];
    unsigned q[8];
    const float xs[4] = {xv.x, xv.y, xv.z, xv.w};
#pragma unroll
    for (int h = 0; h < 4; ++h) {
      const float v = xs[h];
      const float d0 = fabsf(v + 1.f), d1 = fabsf(v), d2 = fabsf(v - 1.f);
      const float b0 = (d0 < 1.f) ? (1.f - d0) * (1.f - d0) : 0.f;
      const float b1 = (d1 < 1.f) ? (1.f - d1) * (1.f - d1) : 0.f;
      const float b2 = (d2 < 1.f) ? (1.f - d2) * (1.f - d2) : 0.f;
      const float inv = 1.f / (b0 + b1 + b2 + 1e-6f);
      q[h * 2 + 0] = (unsigned)f2bf(v) | ((unsigned)f2bf(b0 * inv) << 16);
      q[h * 2 + 1] = (unsigned)f2bf(b1 * inv) | ((unsigned)f2bf(b2 * inv) << 16);
    }
    uint4* dst = (uint4*)(Aaug + (size_t)id4 * 16);
    uint4 u0, u1;
    u0.x = q[0]; u0.y = q[1]; u0.z = q[2]; u0.w = q[3];
    u1.x = q[4]; u1.y = q[5]; u1.z = q[6]; u1.w = q[7];
    dst[0] = u0;
    dst[1] = u1;
  } else if (b < 8192 + 4096) {
    const int id = (b - 8192) * 256 + threadIdx.x;  // over DOUT*DIN
    ushort4 o;
    o.x = f2bf(bw[id]);
    o.y = f2bf(sw[(size_t)id * 3 + 0]);
    o.z = f2bf(sw[(size_t)id * 3 + 1]);
    o.w = f2bf(sw[(size_t)id * 3 + 2]);
    ((ushort4*)Waug)[id] = o;
  } else {
    const int id = (b - 8192 - 4096) * 256 + threadIdx.x;  // 0..131071
    const int plane = id >> 16;   // 0 = hi, 1 = lo
    const int e = id & 65535;
    float srcv;
    ushort* dst;
    int off;
    if (e < SEH * DOUT) { srcv = w1[e]; off = e; dst = plane ? w1lo : w1b; }
    else { srcv = w2[e - SEH * DOUT]; off = e - SEH * DOUT; dst = plane ? w2lo : w2b; }
    const unsigned short hi = f2bf(srcv);
    if (!plane) {
      dst[off] = hi;
    } else {
      union { unsigned u; float f; } hv;
      hv.u = ((unsigned)hi) << 16;
      dst[off] = f2bf(srcv - hv.f);
    }
  }
}

#define WAITVM(N) asm volatile("s_waitcnt vmcnt(" #N ")" ::: "memory")
#define SB0() __builtin_amdgcn_sched_barrier(0)

// Full-K GEMM: C = A[8192x4096] * B[1024x4096]^T, f32 out direct to d_out.
// 128x128 tile, 4 waves (2Mx2N, per-wave 64x64 = acc[4][4]), BK=64,
// double-buffered 64KB LDS -> 2 blocks/CU.
// RACE-FREE BY CONSTRUCTION: full vmcnt(0) drain at every tile top (after
// issuing kt+1's staging). Invariant: at every entry barrier, ZERO LDS-DMA is
// in flight; buffers are only read between entry/exit barriers; swap after
// exit barrier. The counted WAITVM(8) variant (R10..R19) showed build- and
// replay-dependent absmax wobble -- a HW-level retirement race the m97-class
// full-drain structure never exhibited. Staging latency is hidden by the
// second resident block per CU (m114 cross-block TLP).
__global__ __launch_bounds__(256, 2) void gemm_ns(const ushort* __restrict__ A,
                                                  const ushort* __restrict__ B,
                                                  float* __restrict__ C) {
  __shared__ ushort As[2][128 * BK];  // 2 x 16 KB
  __shared__ ushort Bs[2][128 * BK];  // 2 x 16 KB
  const int tid = threadIdx.x;
  const int wid = tid >> 6, lane = tid & 63;
  const int l16 = lane & 15, lk = lane >> 4;
  const int wm = wid >> 1, wn = wid & 1;  // 2M x 2N wave grid

  // T1: XCD chunked swizzle (512 blocks, 64 per XCD; bn inner -> A-panel reuse)
  const int g = (blockIdx.x & 7) * 64 + (blockIdx.x >> 3);
  const int bm = g >> 3;  // 0..63
  const int bn = g & 7;   // 0..7

  const ushort* Ab = A + (size_t)bm * 128 * KAUG;
  const ushort* Bb = B + (size_t)bn * 128 * KAUG;

  const int lrow = lane >> 3;         // 0..7
  const int lcb = (lane & 7) ^ lrow;  // inverse-swizzled source col-block

  const int aBase = (wm * 64 + l16) * 64;
  const int bBase = (wn * 64 + l16) * 64;
  const int sw0 = ((l16 & 4) << 3) + ((lk ^ (l16 & 3)) << 3);
  const int sw1 = sw0 ^ 32;

  f32x4 acc[4][4] = {};

#define STAGE_A(kt, buf, r)                                                     \
  __builtin_amdgcn_global_load_lds(                                             \
      (const __attribute__((address_space(1))) void*)(Ab +                      \
          (size_t)((r) * 32 + wid * 8 + lrow) * KAUG + (kt) * BK + lcb * 8),    \
      (__attribute__((address_space(3))) void*)(&As[buf][((r) * 256 + wid * 64) * 8]), \
      16, 0, 0)
#define STAGE_B(kt, buf, r)                                                     \
  __builtin_amdgcn_global_load_lds(                                             \
      (const __attribute__((address_space(1))) void*)(Bb +                      \
          (size_t)((r) * 32 + wid * 8 + lrow) * KAUG + (kt) * BK + lcb * 8),    \
      (__attribute__((address_space(3))) void*)(&Bs[buf][((r) * 256 + wid * 64) * 8]), \
      16, 0, 0)
#define STAGE_ALL(kt, buf)                                                      \
  do {                                                                          \
    STAGE_A(kt, buf, 0); STAGE_A(kt, buf, 1); STAGE_A(kt, buf, 2); STAGE_A(kt, buf, 3); \
    STAGE_B(kt, buf, 0); STAGE_B(kt, buf, 1); STAGE_B(kt, buf, 2); STAGE_B(kt, buf, 3); \
  } while (0)

#define TILE(kt, CB, NB)                                                        \
  do {                                                                          \
    if ((kt) < NKT - 1) STAGE_ALL((kt) + 1, NB);                                \
    SB0();                                                                      \
    WAITVM(0);  /* full drain: zero LDS-DMA in flight at the barrier */         \
    __builtin_amdgcn_s_barrier();                                               \
    SB0();  /* reads stay below the entry barrier */                            \
    bf16x8 af[4][2], bfr[4][2];                                                 \
    _Pragma("unroll")                                                           \
    for (int m = 0; m < 4; ++m) {                                               \
      af[m][0] = *(const bf16x8*)&As[CB][aBase + m * 1024 + sw0];               \
      af[m][1] = *(const bf16x8*)&As[CB][aBase + m * 1024 + sw1];               \
    }                                                                           \
    _Pragma("unroll")                                                           \
    for (int n = 0; n < 4; ++n) {                                               \
      bfr[n][0] = *(const bf16x8*)&Bs[CB][bBase + n * 1024 + sw0];              \
      bfr[n][1] = *(const bf16x8*)&Bs[CB][bBase + n * 1024 + sw1];              \
    }                                                                           \
    __builtin_amdgcn_s_setprio(1);                                              \
    _Pragma("unroll")                                                           \
    for (int k2 = 0; k2 < 2; ++k2)                                              \
      _Pragma("unroll")                                                         \
      for (int m = 0; m < 4; ++m)                                               \
        _Pragma("unroll")                                                       \
        for (int n = 0; n < 4; ++n)                                             \
          acc[m][n] = __builtin_amdgcn_mfma_f32_16x16x32_bf16(                  \
              af[m][k2], bfr[n][k2], acc[m][n], 0, 0, 0);                       \
    __builtin_amdgcn_s_setprio(0);                                              \
    SB0();  /* nothing sinks past the exit barrier */                           \
    __builtin_amdgcn_s_barrier();                                               \
    SB0();  /* next-tile staging stays below the exit barrier */                \
  } while (0)

  STAGE_ALL(0, 0);

  for (int kt2 = 0; kt2 < NKT; kt2 += 2) {
    TILE(kt2, 0, 1);
    TILE(kt2 + 1, 1, 0);
  }

  float* Cb = C + (size_t)(bm * 128 + wm * 64) * DOUT + bn * 128 + wn * 64;
#pragma unroll
  for (int m = 0; m < 4; ++m)
#pragma unroll
    for (int n = 0; n < 4; ++n)
#pragma unroll
      for (int j = 0; j < 4; ++j)
        Cb[(size_t)(m * 16 + lk * 4 + j) * DOUT + n * 16 + l16] = acc[m][n][j];
}

// Fused LayerNorm + SE (both SE matmuls on MFMA, hi+lo weight planes).
// 16 tokens/block, 4 waves. In-place on out (f32).
__global__ __launch_bounds__(256) void ln_se_mfma(
    float* __restrict__ out,
    const float* __restrict__ ln_w, const float* __restrict__ ln_b,
    const ushort* __restrict__ w1b, const ushort* __restrict__ w1lo,
    const float* __restrict__ se_b1,
    const ushort* __restrict__ w2b, const ushort* __restrict__ w2lo,
    const float* __restrict__ se_b2) {
  __shared__ float Yl[16 * 1028];       // 16 tokens x 1024 (+4 pad) f32
  __shared__ float Hpart[4][512];       // per-wave SE1 partials (16x32)
  __shared__ unsigned Hb[256];          // H packed bf16 [16 tok][16 u32]
  const int tid = threadIdx.x;
  const int w = tid >> 6, lane = tid & 63;
  const int l16 = lane & 15, lk = lane >> 4;
  const int tok0 = blockIdx.x * 16;

  float4 lwv[4], lbv[4];
#pragma unroll
  for (int q = 0; q < 4; ++q) {
    lwv[q] = ((const float4*)ln_w)[q * 64 + lane];
    lbv[q] = ((const float4*)ln_b)[q * 64 + lane];
  }

  for (int qt = 0; qt < 4; ++qt) {
    const int tl = w * 4 + qt;
    const float4* r0 = (const float4*)(out + (size_t)(tok0 + tl) * DOUT);
    float4 v[4];
#pragma unroll
    for (int q = 0; q < 4; ++q) v[q] = r0[q * 64 + lane];
    float s = 0.f, ss = 0.f;
#pragma unroll
    for (int q = 0; q < 4; ++q) {
      s += v[q].x + v[q].y + v[q].z + v[q].w;
      ss += v[q].x * v[q].x + v[q].y * v[q].y + v[q].z * v[q].z + v[q].w * v[q].w;
    }
#pragma unroll
    for (int m = 32; m; m >>= 1) { s += __shfl_xor(s, m); ss += __shfl_xor(ss, m); }
    const float mu = s * (1.f / (float)DOUT);
    const float inv = rsqrtf(ss * (1.f / (float)DOUT) - mu * mu + 1e-5f);
#pragma unroll
    for (int q = 0; q < 4; ++q) {
      float4 yv;
      yv.x = (v[q].x - mu) * inv * lwv[q].x + lbv[q].x;
      yv.y = (v[q].y - mu) * inv * lwv[q].y + lbv[q].y;
      yv.z = (v[q].z - mu) * inv * lwv[q].z + lbv[q].z;
      yv.w = (v[q].w - mu) * inv * lwv[q].w + lbv[q].w;
      *(float4*)&Yl[tl * 1028 + (q * 64 + lane) * 4] = yv;
    }
  }
  __syncthreads();

  // SE1: H = Y @ w1^T, hi+lo planes. K split across waves (256 each).
  f32x4 acc1[2] = {};
#pragma unroll
  for (int s = 0; s < 8; ++s) {
    const int ks = w * 8 + s;
    const int k = ks * 32 + lk * 8;
    const float* yp = &Yl[l16 * 1028 + k];
    const f32x4 q0 = *(const f32x4*)yp;
    const f32x4 q1 = *(const f32x4*)(yp + 4);
    bf16x8 af;
    af[0] = (__bf16)q0[0]; af[1] = (__bf16)q0[1];
    af[2] = (__bf16)q0[2]; af[3] = (__bf16)q0[3];
    af[4] = (__bf16)q1[0]; af[5] = (__bf16)q1[1];
    af[6] = (__bf16)q1[2]; af[7] = (__bf16)q1[3];
#pragma unroll
    for (int nt = 0; nt < 2; ++nt) {
      const size_t woff = (size_t)(nt * 16 + l16) * 1024 + ks * 32 + lk * 8;
      const bf16x8 bh = *(const bf16x8*)(w1b + woff);
      const bf16x8 bl = *(const bf16x8*)(w1lo + woff);
      acc1[nt] = __builtin_amdgcn_mfma_f32_16x16x32_bf16(af, bh, acc1[nt], 0, 0, 0);
      acc1[nt] = __builtin_amdgcn_mfma_f32_16x16x32_bf16(af, bl, acc1[nt], 0, 0, 0);
    }
  }
#pragma unroll
  for (int nt = 0; nt < 2; ++nt)
#pragma unroll
    for (int j = 0; j < 4; ++j)
      Hpart[w][(lk * 4 + j) * 32 + nt * 16 + l16] = acc1[nt][j];
  __syncthreads();

  {
    const int e2 = tid * 2;
    float h0 = Hpart[0][e2] + Hpart[1][e2] + Hpart[2][e2] + Hpart[3][e2];
    float h1 = Hpart[0][e2 + 1] + Hpart[1][e2 + 1] + Hpart[2][e2 + 1] + Hpart[3][e2 + 1];
    h0 = fmaxf(h0 + se_b1[e2 & 31], 0.f);
    h1 = fmaxf(h1 + se_b1[(e2 & 31) + 1], 0.f);
    Hb[tid] = (unsigned)f2bf(h0) | ((unsigned)f2bf(h1) << 16);
  }
  __syncthreads();

  // SE2: G = H @ w2^T, hi+lo planes. N split across waves (256 each).
  union { uint4 u; bf16x8 v; } ha;
  ha.u = *(const uint4*)&Hb[l16 * 16 + lk * 4];
  const int nbase = w * 256;
#pragma unroll
  for (int nt = 0; nt < 16; ++nt) {
    const int col = nbase + nt * 16 + l16;
    const size_t woff = (size_t)col * 32 + lk * 8;
    const bf16x8 bh = *(const bf16x8*)(w2b + woff);
    const bf16x8 bl = *(const bf16x8*)(w2lo + woff);
    f32x4 gz = {0.f, 0.f, 0.f, 0.f};
    gz = __builtin_amdgcn_mfma_f32_16x16x32_bf16(ha.v, bh, gz, 0, 0, 0);
    gz = __builtin_amdgcn_mfma_f32_16x16x32_bf16(ha.v, bl, gz, 0, 0, 0);
    const float b2 = se_b2[col];
#pragma unroll
    for (int j = 0; j < 4; ++j) {
      const int tl = lk * 4 + j;
      const float sg = 1.f / (1.f + __expf(-(gz[j] + b2)));
      out[(size_t)(tok0 + tl) * DOUT + col] = Yl[tl * 1028 + col] * sg;
    }
  }
}

extern "C" void kernel_launch(void* const* d_in, const int* in_sizes, int n_in,
                              void* d_out, int out_size, void* d_ws, size_t ws_size,
                              hipStream_t stream) {
  const float* x = (const float*)d_in[0];
  const float* bw = (const float*)d_in[1];
  const float* sw = (const float*)d_in[2];
  const float* ln_w = (const float*)d_in[3];
  const float* ln_b = (const float*)d_in[4];
  const float* se_w1 = (const float*)d_in[5];
  const float* se_b1 = (const float*)d_in[6];
  const float* se_w2 = (const float*)d_in[7];
  const float* se_b2 = (const float*)d_in[8];
  float* out = (float*)d_out;

  ushort* Aaug = (ushort*)d_ws;                        // 64 MB
  ushort* Waug = Aaug + (size_t)NTOK * KAUG;           // 8 MB
  ushort* w1b = Waug + (size_t)DOUT * KAUG;            // 64 KB
  ushort* w1lo = w1b + SEH * DOUT;                     // 64 KB
  ushort* w2b = w1lo + SEH * DOUT;                     // 64 KB
  ushort* w2lo = w2b + SEH * DOUT;                     // 64 KB

  prep<<<8192 + 4096 + 512, 256, 0, stream>>>(x, bw, sw, se_w1, se_w2,
                                              Aaug, Waug, w1b, w1lo, w2b, w2lo);
  gemm_ns<<<512, 256, 0, stream>>>(Aaug, Waug, out);
  ln_se_mfma<<<NTOK / 16, 256, 0, stream>>>(out, ln_w, ln_b,
                                            w1b, w1lo, se_b1, w2b, w2lo, se_b2);
}

// Round 21
// 112.433 us; speedup vs baseline: 1.0337x; 1.0337x over previous
//
#include <hip/hip_runtime.h>
#include <hip/hip_bf16.h>
#include <math.h>

typedef __attribute__((ext_vector_type(8))) __bf16 bf16x8;
typedef __attribute__((ext_vector_type(4))) float f32x4;

#define NTOK 8192
#define DIN 1024
#define DOUT 1024
#define KAUG 4096
#define SEH 32

#define BK 64
#define NKT (KAUG / BK)  // 64 K-tiles, no split-K

static __device__ __forceinline__ unsigned short f2bf(float f) {
  union { float f; unsigned u; } v; v.f = f;
  unsigned r = (v.u + 0x7FFFu + ((v.u >> 16) & 1u)) >> 16;
  return (unsigned short)r;
}

// Merged prep:
//  A-part (8192 blocks): 4 elems/thread, 16B read / 32B write per lane.
//  W-part (4096 blocks): row-major Waug pack.
//  SE-part (512 blocks): w1/w2 packed as bf16 HI + LO planes (w = hi + lo).
__global__ __launch_bounds__(256) void prep(const float* __restrict__ x,
                                            const float* __restrict__ bw,
                                            const float* __restrict__ sw,
                                            const float* __restrict__ w1,
                                            const float* __restrict__ w2,
                                            ushort* __restrict__ Aaug,
                                            ushort* __restrict__ Waug,
                                            ushort* __restrict__ w1b,
                                            ushort* __restrict__ w1lo,
                                            ushort* __restrict__ w2b,
                                            ushort* __restrict__ w2lo) {
  const int b = blockIdx.x;
  if (b < 8192) {
    const int id4 = b * 256 + threadIdx.x;  // over NTOK*DIN/4
    const float4 xv = ((const float4*)x)[id4];
    unsigned q[8];
    const float xs[4] = {xv.x, xv.y, xv.z, xv.w};
#pragma unroll
    for (int h = 0; h < 4; ++h) {
      const float v = xs[h];
      const float d0 = fabsf(v + 1.f), d1 = fabsf(v), d2 = fabsf(v - 1.f);
      const float b0 = (d0 < 1.f) ? (1.f - d0) * (1.f - d0) : 0.f;
      const float b1 = (d1 < 1.f) ? (1.f - d1) * (1.f - d1) : 0.f;
      const float b2 = (d2 < 1.f) ? (1.f - d2) * (1.f - d2) : 0.f;
      const float inv = 1.f / (b0 + b1 + b2 + 1e-6f);
      q[h * 2 + 0] = (unsigned)f2bf(v) | ((unsigned)f2bf(b0 * inv) << 16);
      q[h * 2 + 1] = (unsigned)f2bf(b1 * inv) | ((unsigned)f2bf(b2 * inv) << 16);
    }
    uint4* dst = (uint4*)(Aaug + (size_t)id4 * 16);
    uint4 u0, u1;
    u0.x = q[0]; u0.y = q[1]; u0.z = q[2]; u0.w = q[3];
    u1.x = q[4]; u1.y = q[5]; u1.z = q[6]; u1.w = q[7];
    dst[0] = u0;
    dst[1] = u1;
  } else if (b < 8192 + 4096) {
    const int id = (b - 8192) * 256 + threadIdx.x;  // over DOUT*DIN
    ushort4 o;
    o.x = f2bf(bw[id]);
    o.y = f2bf(sw[(size_t)id * 3 + 0]);
    o.z = f2bf(sw[(size_t)id * 3 + 1]);
    o.w = f2bf(sw[(size_t)id * 3 + 2]);
    ((ushort4*)Waug)[id] = o;
  } else {
    const int id = (b - 8192 - 4096) * 256 + threadIdx.x;  // 0..131071
    const int plane = id >> 16;   // 0 = hi, 1 = lo
    const int e = id & 65535;
    float srcv;
    ushort* dst;
    int off;
    if (e < SEH * DOUT) { srcv = w1[e]; off = e; dst = plane ? w1lo : w1b; }
    else { srcv = w2[e - SEH * DOUT]; off = e - SEH * DOUT; dst = plane ? w2lo : w2b; }
    const unsigned short hi = f2bf(srcv);
    if (!plane) {
      dst[off] = hi;
    } else {
      union { unsigned u; float f; } hv;
      hv.u = ((unsigned)hi) << 16;
      dst[off] = f2bf(srcv - hv.f);
    }
  }
}

#define WAITVM(N) asm volatile("s_waitcnt vmcnt(" #N ")" ::: "memory")
#define SB0() __builtin_amdgcn_sched_barrier(0)

// Full-K GEMM: C = A[8192x4096] * B[1024x4096]^T, f32 out direct to d_out.
// 128x128 tile, 4 waves (2Mx2N, per-wave 64x64 = acc[4][4]), BK=64,
// double-buffered 64KB LDS -> 2 blocks/CU.
// Canonical m97 single-barrier loop, race-free by construction:
//   loop top (post-barrier): CB fully staged & visible, zero DMA in flight
//   1. issue STAGE(kt+1 -> NB)   (other buffer; its old readers retired at the
//                                 previous barrier)
//   2. ds_read CB frags + MFMA   (~covers the staging latency)
//   3. WAITVM(0)                 (drain residue -> zero DMA in flight)
//   4. s_barrier; swap           (one barrier per tile)
// Full drain at every barrier = the invariant that fixed R20's replay races;
// issue-early + drain-late recovers the latency the R20 ordering exposed.
__global__ __launch_bounds__(256, 2) void gemm_ns(const ushort* __restrict__ A,
                                                  const ushort* __restrict__ B,
                                                  float* __restrict__ C) {
  __shared__ ushort As[2][128 * BK];  // 2 x 16 KB
  __shared__ ushort Bs[2][128 * BK];  // 2 x 16 KB
  const int tid = threadIdx.x;
  const int wid = tid >> 6, lane = tid & 63;
  const int l16 = lane & 15, lk = lane >> 4;
  const int wm = wid >> 1, wn = wid & 1;  // 2M x 2N wave grid

  // T1: XCD chunked swizzle (512 blocks, 64 per XCD; bn inner -> A-panel reuse)
  const int g = (blockIdx.x & 7) * 64 + (blockIdx.x >> 3);
  const int bm = g >> 3;  // 0..63
  const int bn = g & 7;   // 0..7

  const ushort* Ab = A + (size_t)bm * 128 * KAUG;
  const ushort* Bb = B + (size_t)bn * 128 * KAUG;

  const int lrow = lane >> 3;         // 0..7
  const int lcb = (lane & 7) ^ lrow;  // inverse-swizzled source col-block

  const int aBase = (wm * 64 + l16) * 64;
  const int bBase = (wn * 64 + l16) * 64;
  const int sw0 = ((l16 & 4) << 3) + ((lk ^ (l16 & 3)) << 3);
  const int sw1 = sw0 ^ 32;

  f32x4 acc[4][4] = {};

#define STAGE_A(kt, buf, r)                                                     \
  __builtin_amdgcn_global_load_lds(                                             \
      (const __attribute__((address_space(1))) void*)(Ab +                      \
          (size_t)((r) * 32 + wid * 8 + lrow) * KAUG + (kt) * BK + lcb * 8),    \
      (__attribute__((address_space(3))) void*)(&As[buf][((r) * 256 + wid * 64) * 8]), \
      16, 0, 0)
#define STAGE_B(kt, buf, r)                                                     \
  __builtin_amdgcn_global_load_lds(                                             \
      (const __attribute__((address_space(1))) void*)(Bb +                      \
          (size_t)((r) * 32 + wid * 8 + lrow) * KAUG + (kt) * BK + lcb * 8),    \
      (__attribute__((address_space(3))) void*)(&Bs[buf][((r) * 256 + wid * 64) * 8]), \
      16, 0, 0)
#define STAGE_ALL(kt, buf)                                                      \
  do {                                                                          \
    STAGE_A(kt, buf, 0); STAGE_A(kt, buf, 1); STAGE_A(kt, buf, 2); STAGE_A(kt, buf, 3); \
    STAGE_B(kt, buf, 0); STAGE_B(kt, buf, 1); STAGE_B(kt, buf, 2); STAGE_B(kt, buf, 3); \
  } while (0)

#define TILE(kt, CB, NB)                                                        \
  do {                                                                          \
    if ((kt) < NKT - 1) STAGE_ALL((kt) + 1, NB);  /* issue-early into NB */     \
    SB0();  /* staging stays above the reads (issue order) */                   \
    bf16x8 af[4][2], bfr[4][2];                                                 \
    _Pragma("unroll")                                                           \
    for (int m = 0; m < 4; ++m) {                                               \
      af[m][0] = *(const bf16x8*)&As[CB][aBase + m * 1024 + sw0];               \
      af[m][1] = *(const bf16x8*)&As[CB][aBase + m * 1024 + sw1];               \
    }                                                                           \
    _Pragma("unroll")                                                           \
    for (int n = 0; n < 4; ++n) {                                               \
      bfr[n][0] = *(const bf16x8*)&Bs[CB][bBase + n * 1024 + sw0];              \
      bfr[n][1] = *(const bf16x8*)&Bs[CB][bBase + n * 1024 + sw1];              \
    }                                                                           \
    __builtin_amdgcn_s_setprio(1);                                              \
    _Pragma("unroll")                                                           \
    for (int k2 = 0; k2 < 2; ++k2)                                              \
      _Pragma("unroll")                                                         \
      for (int m = 0; m < 4; ++m)                                               \
        _Pragma("unroll")                                                       \
        for (int n = 0; n < 4; ++n)                                             \
          acc[m][n] = __builtin_amdgcn_mfma_f32_16x16x32_bf16(                  \
              af[m][k2], bfr[n][k2], acc[m][n], 0, 0, 0);                       \
    __builtin_amdgcn_s_setprio(0);                                              \
    SB0();  /* nothing sinks below the drain */                                 \
    WAITVM(0);  /* zero DMA in flight at the barrier */                         \
    __builtin_amdgcn_s_barrier();                                               \
    SB0();  /* next tile's work stays below the barrier */                      \
  } while (0)

  // prologue: stage tile 0, drain, publish
  STAGE_ALL(0, 0);
  WAITVM(0);
  __builtin_amdgcn_s_barrier();
  SB0();

  for (int kt2 = 0; kt2 < NKT; kt2 += 2) {
    TILE(kt2, 0, 1);
    TILE(kt2 + 1, 1, 0);
  }

  float* Cb = C + (size_t)(bm * 128 + wm * 64) * DOUT + bn * 128 + wn * 64;
#pragma unroll
  for (int m = 0; m < 4; ++m)
#pragma unroll
    for (int n = 0; n < 4; ++n)
#pragma unroll
      for (int j = 0; j < 4; ++j)
        Cb[(size_t)(m * 16 + lk * 4 + j) * DOUT + n * 16 + l16] = acc[m][n][j];
}

// Fused LayerNorm + SE (both SE matmuls on MFMA, hi+lo weight planes).
// 16 tokens/block, 4 waves. In-place on out (f32). Byte-identical to R20.
__global__ __launch_bounds__(256) void ln_se_mfma(
    float* __restrict__ out,
    const float* __restrict__ ln_w, const float* __restrict__ ln_b,
    const ushort* __restrict__ w1b, const ushort* __restrict__ w1lo,
    const float* __restrict__ se_b1,
    const ushort* __restrict__ w2b, const ushort* __restrict__ w2lo,
    const float* __restrict__ se_b2) {
  __shared__ float Yl[16 * 1028];       // 16 tokens x 1024 (+4 pad) f32
  __shared__ float Hpart[4][512];       // per-wave SE1 partials (16x32)
  __shared__ unsigned Hb[256];          // H packed bf16 [16 tok][16 u32]
  const int tid = threadIdx.x;
  const int w = tid >> 6, lane = tid & 63;
  const int l16 = lane & 15, lk = lane >> 4;
  const int tok0 = blockIdx.x * 16;

  float4 lwv[4], lbv[4];
#pragma unroll
  for (int q = 0; q < 4; ++q) {
    lwv[q] = ((const float4*)ln_w)[q * 64 + lane];
    lbv[q] = ((const float4*)ln_b)[q * 64 + lane];
  }

  for (int qt = 0; qt < 4; ++qt) {
    const int tl = w * 4 + qt;
    const float4* r0 = (const float4*)(out + (size_t)(tok0 + tl) * DOUT);
    float4 v[4];
#pragma unroll
    for (int q = 0; q < 4; ++q) v[q] = r0[q * 64 + lane];
    float s = 0.f, ss = 0.f;
#pragma unroll
    for (int q = 0; q < 4; ++q) {
      s += v[q].x + v[q].y + v[q].z + v[q].w;
      ss += v[q].x * v[q].x + v[q].y * v[q].y + v[q].z * v[q].z + v[q].w * v[q].w;
    }
#pragma unroll
    for (int m = 32; m; m >>= 1) { s += __shfl_xor(s, m); ss += __shfl_xor(ss, m); }
    const float mu = s * (1.f / (float)DOUT);
    const float inv = rsqrtf(ss * (1.f / (float)DOUT) - mu * mu + 1e-5f);
#pragma unroll
    for (int q = 0; q < 4; ++q) {
      float4 yv;
      yv.x = (v[q].x - mu) * inv * lwv[q].x + lbv[q].x;
      yv.y = (v[q].y - mu) * inv * lwv[q].y + lbv[q].y;
      yv.z = (v[q].z - mu) * inv * lwv[q].z + lbv[q].z;
      yv.w = (v[q].w - mu) * inv * lwv[q].w + lbv[q].w;
      *(float4*)&Yl[tl * 1028 + (q * 64 + lane) * 4] = yv;
    }
  }
  __syncthreads();

  // SE1: H = Y @ w1^T, hi+lo planes. K split across waves (256 each).
  f32x4 acc1[2] = {};
#pragma unroll
  for (int s = 0; s < 8; ++s) {
    const int ks = w * 8 + s;
    const int k = ks * 32 + lk * 8;
    const float* yp = &Yl[l16 * 1028 + k];
    const f32x4 q0 = *(const f32x4*)yp;
    const f32x4 q1 = *(const f32x4*)(yp + 4);
    bf16x8 af;
    af[0] = (__bf16)q0[0]; af[1] = (__bf16)q0[1];
    af[2] = (__bf16)q0[2]; af[3] = (__bf16)q0[3];
    af[4] = (__bf16)q1[0]; af[5] = (__bf16)q1[1];
    af[6] = (__bf16)q1[2]; af[7] = (__bf16)q1[3];
#pragma unroll
    for (int nt = 0; nt < 2; ++nt) {
      const size_t woff = (size_t)(nt * 16 + l16) * 1024 + ks * 32 + lk * 8;
      const bf16x8 bh = *(const bf16x8*)(w1b + woff);
      const bf16x8 bl = *(const bf16x8*)(w1lo + woff);
      acc1[nt] = __builtin_amdgcn_mfma_f32_16x16x32_bf16(af, bh, acc1[nt], 0, 0, 0);
      acc1[nt] = __builtin_amdgcn_mfma_f32_16x16x32_bf16(af, bl, acc1[nt], 0, 0, 0);
    }
  }
#pragma unroll
  for (int nt = 0; nt < 2; ++nt)
#pragma unroll
    for (int j = 0; j < 4; ++j)
      Hpart[w][(lk * 4 + j) * 32 + nt * 16 + l16] = acc1[nt][j];
  __syncthreads();

  {
    const int e2 = tid * 2;
    float h0 = Hpart[0][e2] + Hpart[1][e2] + Hpart[2][e2] + Hpart[3][e2];
    float h1 = Hpart[0][e2 + 1] + Hpart[1][e2 + 1] + Hpart[2][e2 + 1] + Hpart[3][e2 + 1];
    h0 = fmaxf(h0 + se_b1[e2 & 31], 0.f);
    h1 = fmaxf(h1 + se_b1[(e2 & 31) + 1], 0.f);
    Hb[tid] = (unsigned)f2bf(h0) | ((unsigned)f2bf(h1) << 16);
  }
  __syncthreads();

  // SE2: G = H @ w2^T, hi+lo planes. N split across waves (256 each).
  union { uint4 u; bf16x8 v; } ha;
  ha.u = *(const uint4*)&Hb[l16 * 16 + lk * 4];
  const int nbase = w * 256;
#pragma unroll
  for (int nt = 0; nt < 16; ++nt) {
    const int col = nbase + nt * 16 + l16;
    const size_t woff = (size_t)col * 32 + lk * 8;
    const bf16x8 bh = *(const bf16x8*)(w2b + woff);
    const bf16x8 bl = *(const bf16x8*)(w2lo + woff);
    f32x4 gz = {0.f, 0.f, 0.f, 0.f};
    gz = __builtin_amdgcn_mfma_f32_16x16x32_bf16(ha.v, bh, gz, 0, 0, 0);
    gz = __builtin_amdgcn_mfma_f32_16x16x32_bf16(ha.v, bl, gz, 0, 0, 0);
    const float b2 = se_b2[col];
#pragma unroll
    for (int j = 0; j < 4; ++j) {
      const int tl = lk * 4 + j;
      const float sg = 1.f / (1.f + __expf(-(gz[j] + b2)));
      out[(size_t)(tok0 + tl) * DOUT + col] = Yl[tl * 1028 + col] * sg;
    }
  }
}

extern "C" void kernel_launch(void* const* d_in, const int* in_sizes, int n_in,
                              void* d_out, int out_size, void* d_ws, size_t ws_size,
                              hipStream_t stream) {
  const float* x = (const float*)d_in[0];
  const float* bw = (const float*)d_in[1];
  const float* sw = (const float*)d_in[2];
  const float* ln_w = (const float*)d_in[3];
  const float* ln_b = (const float*)d_in[4];
  const float* se_w1 = (const float*)d_in[5];
  const float* se_b1 = (const float*)d_in[6];
  const float* se_w2 = (const float*)d_in[7];
  const float* se_b2 = (const float*)d_in[8];
  float* out = (float*)d_out;

  ushort* Aaug = (ushort*)d_ws;                        // 64 MB
  ushort* Waug = Aaug + (size_t)NTOK * KAUG;           // 8 MB
  ushort* w1b = Waug + (size_t)DOUT * KAUG;            // 64 KB
  ushort* w1lo = w1b + SEH * DOUT;                     // 64 KB
  ushort* w2b = w1lo + SEH * DOUT;                     // 64 KB
  ushort* w2lo = w2b + SEH * DOUT;                     // 64 KB

  prep<<<8192 + 4096 + 512, 256, 0, stream>>>(x, bw, sw, se_w1, se_w2,
                                              Aaug, Waug, w1b, w1lo, w2b, w2lo);
  gemm_ns<<<512, 256, 0, stream>>>(Aaug, Waug, out);
  ln_se_mfma<<<NTOK / 16, 256, 0, stream>>>(out, ln_w, ln_b,
                                            w1b, w1lo, se_b1, w2b, w2lo, se_b2);
}